// Round 9
// baseline (506.820 us; speedup 1.0000x reference)
//
#include <hip/hip_runtime.h>
#include <hip/hip_fp16.h>
#include <hip/hip_cooperative_groups.h>

namespace cg = cooperative_groups;

#define N_NODES 100000
#define IN_DIM 256
#define OUT_DIM 64
#define NT 782                 // dst/src tiles of 128 nodes
#define NB 256                 // count/scatter edge-chunking blocks
#define SCAN_M (NT * NB)       // 200192 flattened counts per array
#define NCH 196                // scan chunks of 1024: ceil(200192/1024)
#define GRID 1024              // cooperative grid (4 blocks/CU x 256 CUs)
#define B_LD 264               // W LDS leading dim (x2B = 528 = 33*16, b128-aligned)

typedef _Float16 half8 __attribute__((ext_vector_type(8)));
typedef float f32x4 __attribute__((ext_vector_type(4)));

// exclusive scan of NCH(196) global ints into LDS, 256 threads; wt = 4-int LDS scratch
__device__ __forceinline__ void bscan_nch(const int* __restrict__ g, int* __restrict__ out,
                                          int* wt, int t) {
    const int lane = t & 63, wv = t >> 6;
    int v = (t < NCH) ? g[t] : 0;
    int incl = v;
#pragma unroll
    for (int off = 1; off < 64; off <<= 1) {
        int y = __shfl_up(incl, off);
        if (lane >= off) incl += y;
    }
    if (lane == 63) wt[wv] = incl;
    __syncthreads();
    int woff = 0;
    for (int x = 0; x < wv; ++x) woff += wt[x];
    if (t < NCH) out[t] = woff + incl - v;
    __syncthreads();
}

// ======================= cooperative mega-kernel =======================
// P1: count (blocks<NB) || gemm (blocks>=NB)   P2: scan   P3: scatter   P4: tile
__global__ __launch_bounds__(256, 4) void coop_kernel(
        const int* __restrict__ src, const int* __restrict__ dst,
        const float* __restrict__ hmat, const float* __restrict__ W,
        int* __restrict__ CD, int* __restrict__ CS,
        int* __restrict__ BSD, int* __restrict__ BSS,
        int* __restrict__ binnedD, unsigned char* __restrict__ srcb,
        int* __restrict__ csr, int* __restrict__ offs, int* __restrict__ cnt,
        float* __restrict__ norm_src, __half* __restrict__ xh,
        int E, int CH4) {
    cg::grid_group grid = cg::this_grid();
    __shared__ __align__(16) char smem[64 * B_LD * 2];   // 33792 B union
    const int t = threadIdx.x;
    const int blk = blockIdx.x;
    const int lane = t & 63;
    const int wv = t >> 6;
    const int nblk = gridDim.x;

    // ---------------- P1a: count (blocks < NB) ----------------
    if (blk < NB) {
        int* hd = (int*)smem;          // NT
        int* hs = hd + NT;             // NT
        for (int i = t; i < NT; i += 256) { hd[i] = 0; hs[i] = 0; }
        __syncthreads();
        const int E4 = E >> 2;
        const int lo4 = blk * CH4;
        int hi4 = lo4 + CH4; if (hi4 > E4) hi4 = E4;
        const int4* s4 = (const int4*)src;
        const int4* d4 = (const int4*)dst;
        for (int k = lo4 + t; k < hi4; k += 256) {
            int4 a = s4[k], c = d4[k];
            atomicAdd(&hs[a.x >> 7], 1); atomicAdd(&hs[a.y >> 7], 1);
            atomicAdd(&hs[a.z >> 7], 1); atomicAdd(&hs[a.w >> 7], 1);
            atomicAdd(&hd[c.x >> 7], 1); atomicAdd(&hd[c.y >> 7], 1);
            atomicAdd(&hd[c.z >> 7], 1); atomicAdd(&hd[c.w >> 7], 1);
        }
        if (blk == NB - 1) {           // scalar tail (E%4)
            for (int i = E4 * 4 + t; i < E; i += 256) {
                atomicAdd(&hs[src[i] >> 7], 1);
                atomicAdd(&hd[dst[i] >> 7], 1);
            }
        }
        __syncthreads();
        for (int i = t; i < NT; i += 256) {
            CD[i * NB + blk] = hd[i];
            CS[i * NB + blk] = hs[i];
        }
    } else {
        // ---------------- P1b: MFMA gemm, xh = fp16(h @ W) un-normalized ----------------
        _Float16* sB = (_Float16*)smem;    // 64 x B_LD
#pragma unroll
        for (int it = 0; it < 16; ++it) {
            int f = t + it * 256;
            int k = f >> 4;
            int n4 = (f & 15) * 4;
            float4 v = *(const float4*)(W + (size_t)k * OUT_DIM + n4);
            sB[(n4 + 0) * B_LD + k] = (_Float16)v.x;
            sB[(n4 + 1) * B_LD + k] = (_Float16)v.y;
            sB[(n4 + 2) * B_LD + k] = (_Float16)v.z;
            sB[(n4 + 3) * B_LD + k] = (_Float16)v.w;
        }
        __syncthreads();
        const int m16 = lane & 15;
        const int kq = lane >> 4;
        const int gw = (blk - NB) * 4 + wv;
        const int gstride = (nblk - NB) * 4;
        for (int u = gw; u < N_NODES / 16; u += gstride) {   // 6250 16-row units
            const float* arow = hmat + (size_t)(u * 16 + m16) * IN_DIM;
            f32x4 acc[4] = {{0,0,0,0},{0,0,0,0},{0,0,0,0},{0,0,0,0}};
#pragma unroll
            for (int kb = 0; kb < 8; ++kb) {
                const int koff = kb * 32 + kq * 8;
                float4 alo = *(const float4*)(arow + koff);
                float4 ahi = *(const float4*)(arow + koff + 4);
                _Float16 af[8];
                af[0] = (_Float16)alo.x; af[1] = (_Float16)alo.y;
                af[2] = (_Float16)alo.z; af[3] = (_Float16)alo.w;
                af[4] = (_Float16)ahi.x; af[5] = (_Float16)ahi.y;
                af[6] = (_Float16)ahi.z; af[7] = (_Float16)ahi.w;
                half8 a = *(half8*)af;
#pragma unroll
                for (int ni = 0; ni < 4; ++ni) {
                    half8 b = *(const half8*)&sB[(ni * 16 + m16) * B_LD + koff];
                    acc[ni] = __builtin_amdgcn_mfma_f32_16x16x32_f16(a, b, acc[ni], 0, 0, 0);
                }
            }
            const int rq = kq * 4;
#pragma unroll
            for (int ni = 0; ni < 4; ++ni) {
                int col = ni * 16 + m16;
#pragma unroll
                for (int r = 0; r < 4; ++r) {
                    int row = u * 16 + rq + r;
                    xh[(size_t)row * OUT_DIM + col] = __float2half(acc[ni][r]);
                }
            }
        }
    }
    grid.sync();

    // ---------------- P2: scan CD and CS in 1024-chunks; raw sums -> BSD/BSS ----------------
    {
        int* wt = (int*)smem;   // 4 ints
        for (int c = blk; c < 2 * NCH; c += nblk) {
            int* arr = (c < NCH) ? CD : CS;
            int* bs  = (c < NCH) ? BSD : BSS;
            int cid  = (c < NCH) ? c : c - NCH;
            int base = cid * 1024 + t * 4;
            int pre[4], s = 0;
#pragma unroll
            for (int r = 0; r < 4; ++r) {
                int v = (base + r < SCAN_M) ? arr[base + r] : 0;
                pre[r] = s; s += v;
            }
            int incl = s;
#pragma unroll
            for (int off = 1; off < 64; off <<= 1) {
                int y = __shfl_up(incl, off);
                if (lane >= off) incl += y;
            }
            if (lane == 63) wt[wv] = incl;
            __syncthreads();
            int woff = 0;
            for (int x = 0; x < wv; ++x) woff += wt[x];
            int bexcl = woff + incl - s;
#pragma unroll
            for (int r = 0; r < 4; ++r)
                if (base + r < SCAN_M) arr[base + r] = bexcl + pre[r];
            if (t == 0) bs[cid] = wt[0] + wt[1] + wt[2] + wt[3];
            __syncthreads();
        }
    }
    grid.sync();

    // ---------------- P3: deterministic scatter (blocks < NB) ----------------
    if (blk < NB) {
        int* curD = (int*)smem;          // NT
        int* curS = curD + NT;           // NT
        int* sBSD = curS + NT;           // NCH (pad 256)
        int* sBSS = sBSD + 256;          // NCH (pad 256)
        int* wt   = sBSS + 256;          // 4
        bscan_nch(BSD, sBSD, wt, t);
        bscan_nch(BSS, sBSS, wt, t);
        for (int i = t; i < NT; i += 256) {
            int idx = i * NB + blk;
            curD[i] = CD[idx] + sBSD[idx >> 10];
            curS[i] = CS[idx] + sBSS[idx >> 10];
        }
        __syncthreads();
        const int E4 = E >> 2;
        const int lo4 = blk * CH4;
        int hi4 = lo4 + CH4; if (hi4 > E4) hi4 = E4;
        const int4* s4 = (const int4*)src;
        const int4* d4 = (const int4*)dst;
        for (int k = lo4 + t; k < hi4; k += 256) {
            int4 a = s4[k], c = d4[k];
            int p;
            p = atomicAdd(&curD[c.x >> 7], 1); binnedD[p] = (a.x << 7) | (c.x & 127);
            p = atomicAdd(&curD[c.y >> 7], 1); binnedD[p] = (a.y << 7) | (c.y & 127);
            p = atomicAdd(&curD[c.z >> 7], 1); binnedD[p] = (a.z << 7) | (c.z & 127);
            p = atomicAdd(&curD[c.w >> 7], 1); binnedD[p] = (a.w << 7) | (c.w & 127);
            p = atomicAdd(&curS[a.x >> 7], 1); srcb[p] = (unsigned char)(a.x & 127);
            p = atomicAdd(&curS[a.y >> 7], 1); srcb[p] = (unsigned char)(a.y & 127);
            p = atomicAdd(&curS[a.z >> 7], 1); srcb[p] = (unsigned char)(a.z & 127);
            p = atomicAdd(&curS[a.w >> 7], 1); srcb[p] = (unsigned char)(a.w & 127);
        }
        if (blk == NB - 1) {
            for (int i = E4 * 4 + t; i < E; i += 256) {
                int s = src[i], d = dst[i];
                int p = atomicAdd(&curD[d >> 7], 1);
                binnedD[p] = (s << 7) | (d & 127);
                int ps = atomicAdd(&curS[s >> 7], 1);
                srcb[ps] = (unsigned char)(s & 127);
            }
        }
    }
    grid.sync();

    // ---------------- P4: per-tile CSR-ify + norm_src ----------------
    {
        int* hh   = (int*)smem;          // 128
        int* cur  = hh + 128;            // 128
        int* sBSD = cur + 128;           // NCH (pad 224)
        int* sBSS = sBSD + 224;          // NCH (pad 224)
        int* wt   = sBSS + 224;          // 4
        int* w0t  = wt + 4;              // 1
        bscan_nch(BSD, sBSD, wt, t);
        bscan_nch(BSS, sBSS, wt, t);
        for (int bin = blk; bin < NT; bin += nblk) {
            const int i0 = bin * NB;
            if (t < 128) hh[t] = 0;
            __syncthreads();
            // dst phase
            const int base = CD[i0] + sBSD[i0 >> 10];
            const int next = (bin + 1 < NT) ? (CD[i0 + NB] + sBSD[(i0 + NB) >> 10]) : E;
            const int m = next - base;
            for (int k = t; k < m; k += 256) atomicAdd(&hh[binnedD[base + k] & 127], 1);
            __syncthreads();
            int v = (t < 128) ? hh[t] : 0;
            int incl = v;
#pragma unroll
            for (int off = 1; off < 64; off <<= 1) {
                int y = __shfl_up(incl, off);
                if (lane >= off) incl += y;
            }
            if (t == 63) *w0t = incl;
            __syncthreads();
            int excl = incl - v + ((t >= 64 && t < 128) ? *w0t : 0);
            if (t < 128) {
                cur[t] = excl;
                int node = bin * 128 + t;
                if (node < N_NODES) { offs[node] = base + excl; cnt[node] = v; }
            }
            __syncthreads();
            for (int k = t; k < m; k += 256) {
                int rec = binnedD[base + k];
                int p = atomicAdd(&cur[rec & 127], 1);
                csr[base + p] = rec >> 7;
            }
            __syncthreads();
            // src phase -> norm_src
            if (t < 128) hh[t] = 0;
            __syncthreads();
            const int sb = CS[i0] + sBSS[i0 >> 10];
            const int sn = (bin + 1 < NT) ? (CS[i0 + NB] + sBSS[(i0 + NB) >> 10]) : E;
            const int sm = sn - sb;
            for (int k = t; k < sm; k += 256) atomicAdd(&hh[srcb[sb + k]], 1);
            __syncthreads();
            if (t < 128) {
                int node = bin * 128 + t;
                if (node < N_NODES) {
                    int d = hh[t];
                    norm_src[node] = rsqrtf((float)(d < 1 ? 1 : d));
                }
            }
            __syncthreads();
        }
    }
}

// ---------------- aggregate: one wave per node; per-edge x row scaled by norm_src[s] ----------------
__global__ __launch_bounds__(256) void aggregate_kernel(const int* __restrict__ offs,
                                                        const int* __restrict__ cnt,
                                                        const int* __restrict__ csr,
                                                        const __half* __restrict__ xh,
                                                        const float* __restrict__ norm_src,
                                                        const float* __restrict__ b,
                                                        float* __restrict__ out) {
    const int t = threadIdx.x;
    const int lane = t & 63;
    const int wid = t >> 6;
    const int node = blockIdx.x * 4 + wid;          // 25000*4 == N_NODES exactly
    const int g = lane >> 3;
    const int c = lane & 7;

    const int start = offs[node];
    const int n = cnt[node];

    float acc[8] = {0.f, 0.f, 0.f, 0.f, 0.f, 0.f, 0.f, 0.f};
    for (int base = 0; base < n; base += 64) {
        int k = base + lane;
        int sidx = (k < n) ? csr[start + k] : 0;
        int m = n - base; if (m > 64) m = 64;
        for (int rb = 0; rb < m; rb += 32) {
            uint4 raw[4]; float wq[4];
#pragma unroll
            for (int q = 0; q < 4; ++q) {
                int e = rb + 8 * q + g;              // <= 63 always
                int s = __shfl(sidx, e);
                bool val = e < m;
                s = val ? s : 0;
                float ns = norm_src[s];
                wq[q] = val ? ns : 0.f;
                raw[q] = *(const uint4*)(xh + (size_t)s * OUT_DIM + 8 * c);
            }
#pragma unroll
            for (int q = 0; q < 4; ++q) {
                const __half2* hp = (const __half2*)&raw[q];
#pragma unroll
                for (int p = 0; p < 4; ++p) {
                    float2 f = __half22float2(hp[p]);
                    acc[2 * p]     = fmaf(wq[q], f.x, acc[2 * p]);
                    acc[2 * p + 1] = fmaf(wq[q], f.y, acc[2 * p + 1]);
                }
            }
        }
    }

#pragma unroll
    for (int off = 8; off < 64; off <<= 1) {
#pragma unroll
        for (int p = 0; p < 8; ++p)
            acc[p] += __shfl_xor(acc[p], off);
    }

    if (g == 0) {   // lanes 0..7 hold full sums for cols c*8..c*8+7
        float nrm = rsqrtf((float)(n < 1 ? 1 : n));
        float4 bv0 = *(const float4*)&b[c * 8];
        float4 bv1 = *(const float4*)&b[c * 8 + 4];
        float4 r0, r1;
        r0.x = fmaxf(fmaf(acc[0], nrm, bv0.x), 0.f);
        r0.y = fmaxf(fmaf(acc[1], nrm, bv0.y), 0.f);
        r0.z = fmaxf(fmaf(acc[2], nrm, bv0.z), 0.f);
        r0.w = fmaxf(fmaf(acc[3], nrm, bv0.w), 0.f);
        r1.x = fmaxf(fmaf(acc[4], nrm, bv1.x), 0.f);
        r1.y = fmaxf(fmaf(acc[5], nrm, bv1.y), 0.f);
        r1.z = fmaxf(fmaf(acc[6], nrm, bv1.z), 0.f);
        r1.w = fmaxf(fmaf(acc[7], nrm, bv1.w), 0.f);
        float4* orow = (float4*)(out + (size_t)node * OUT_DIM + c * 8);
        orow[0] = r0;
        orow[1] = r1;
    }
}

extern "C" void kernel_launch(void* const* d_in, const int* in_sizes, int n_in,
                              void* d_out, int out_size, void* d_ws, size_t ws_size,
                              hipStream_t stream) {
    const float* h   = (const float*)d_in[0];
    const int*   src = (const int*)d_in[1];
    const int*   dst = (const int*)d_in[2];
    const float* W   = (const float*)d_in[3];
    const float* b   = (const float*)d_in[4];
    float* out = (float*)d_out;
    int E = in_sizes[1];
    int CH4 = ((E >> 2) + NB - 1) / NB;

    // workspace layout (16B aligned), ~30 MB; everything written before read
    char* ws = (char*)d_ws;
    int*           CD       = (int*)(ws);                     // 200192 ints
    int*           CS       = (int*)(ws + 800768);            // 200192 ints
    int*           BSD      = (int*)(ws + 1601536);           // 196 ints (pad 1 KB)
    int*           BSS      = (int*)(ws + 1602560);           // 196 ints (pad 1 KB)
    int*           binnedD  = (int*)(ws + 1603584);           // E ints (6.4 MB)
    unsigned char* srcb     = (unsigned char*)(ws + 8003584); // E bytes (1.6 MB)
    int*           csr      = (int*)(ws + 9603584);           // E ints (6.4 MB)
    int*           offs     = (int*)(ws + 16003584);          // N ints
    int*           cntA     = (int*)(ws + 16403584);          // N ints
    float*         norm_src = (float*)(ws + 16803584);        // N floats
    __half*        xh       = (__half*)(ws + 17203584);       // N*64 halfs (12.8 MB)

    // clamp cooperative grid to what co-residency allows (expect 4/CU -> 1024)
    int maxB = 4;
    hipOccupancyMaxActiveBlocksPerMultiprocessor(&maxB, (const void*)coop_kernel, 256, 0);
    if (maxB < 1) maxB = 1;
    int gridBlocks = 256 * maxB;
    if (gridBlocks > GRID) gridBlocks = GRID;
    if (gridBlocks <= NB) gridBlocks = NB + 256;   // ensure gemm blocks exist

    void* cargs[] = {(void*)&src, (void*)&dst, (void*)&h, (void*)&W,
                     (void*)&CD, (void*)&CS, (void*)&BSD, (void*)&BSS,
                     (void*)&binnedD, (void*)&srcb, (void*)&csr,
                     (void*)&offs, (void*)&cntA, (void*)&norm_src, (void*)&xh,
                     (void*)&E, (void*)&CH4};
    hipLaunchCooperativeKernel((const void*)coop_kernel, dim3(gridBlocks), dim3(256),
                               cargs, 0, stream);

    aggregate_kernel<<<N_NODES / 4, 256, 0, stream>>>(offs, cntA, csr, xh, norm_src, b, out);
}

// Round 12
// 321.221 us; speedup vs baseline: 1.5778x; 1.5778x over previous
//
#include <hip/hip_runtime.h>
#include <hip/hip_fp16.h>

#define N_NODES 100000
#define IN_DIM 256
#define OUT_DIM 64
#define NT 782                 // dst/src tiles of 128 nodes
#define NB 256                 // binning blocks
#define SCHUNK 4096            // scan chunk: 256 threads * 16
#define SB ((NT * NB + SCHUNK - 1) / SCHUNK)   // 49 scan blocks per array
#define SCAN_M (NT * NB)       // 200192

typedef _Float16 half8 __attribute__((ext_vector_type(8)));
typedef float f32x4 __attribute__((ext_vector_type(4)));

// ---------------- pass 1: per-block LDS histograms of dst>>7 and src>>7 ----------------
__global__ __launch_bounds__(256) void count_kernel(const int* __restrict__ src,
                                                    const int* __restrict__ dst,
                                                    int* __restrict__ CD, int* __restrict__ CS,
                                                    int E, int chunk) {
    __shared__ int hd[NT], hs[NT];
    const int t = threadIdx.x, blk = blockIdx.x;
    for (int i = t; i < NT; i += 256) { hd[i] = 0; hs[i] = 0; }
    __syncthreads();
    const int lo = blk * chunk;
    int hi = lo + chunk; if (hi > E) hi = E;
    for (int i = lo + t; i < hi; i += 256) {
        atomicAdd(&hd[dst[i] >> 7], 1);
        atomicAdd(&hs[src[i] >> 7], 1);
    }
    __syncthreads();
    for (int i = t; i < NT; i += 256) {
        CD[i * NB + blk] = hd[i];
        CS[i * NB + blk] = hs[i];
    }
}

// ---------------- pass 2a: chunk-local exclusive scan of CD and CS (in place) ----------------
__global__ __launch_bounds__(256) void scan_blocks_kernel(int* __restrict__ CD, int* __restrict__ CS,
                                                          int* __restrict__ BSD, int* __restrict__ BSS) {
    int cid = blockIdx.x;
    int* arr; int* bs;
    if (cid < SB) { arr = CD; bs = BSD; } else { arr = CS; bs = BSS; cid -= SB; }
    const int t = threadIdx.x;
    const int base = cid * SCHUNK + t * 16;
    int pre[16];
    int s = 0;
#pragma unroll
    for (int r = 0; r < 16; ++r) {
        int v = (base + r < SCAN_M) ? arr[base + r] : 0;
        pre[r] = s; s += v;
    }
    const int lane = t & 63;
    int incl = s;
#pragma unroll
    for (int off = 1; off < 64; off <<= 1) {
        int y = __shfl_up(incl, off);
        if (lane >= off) incl += y;
    }
    int wave_excl = incl - s;
    __shared__ int wtot[4];
    if (lane == 63) wtot[t >> 6] = incl;
    __syncthreads();
    int woff = 0;
    for (int w = 0; w < (t >> 6); ++w) woff += wtot[w];
    int bexcl = woff + wave_excl;
#pragma unroll
    for (int r = 0; r < 16; ++r)
        if (base + r < SCAN_M) arr[base + r] = bexcl + pre[r];
    if (t == 0) bs[cid] = wtot[0] + wtot[1] + wtot[2] + wtot[3];
}

// ---------------- pass 2b: scan the 49 chunk sums of both arrays (2 waves) ----------------
__global__ void scan_sums_kernel(int* __restrict__ BSD, int* __restrict__ BSS) {
    const int t = threadIdx.x;
    const int lane = t & 63;
    int* bs = (t < 64) ? BSD : BSS;
    int v = (lane < SB) ? bs[lane] : 0;
    int incl = v;
#pragma unroll
    for (int off = 1; off < 64; off <<= 1) {
        int y = __shfl_up(incl, off);
        if (lane >= off) incl += y;
    }
    if (lane < SB) bs[lane] = incl - v;
}

// ---------------- pass 3: deterministic scatter into dst-binned ints + src-binned bytes ----------------
__global__ __launch_bounds__(256) void scatter_kernel(const int* __restrict__ src,
                                                      const int* __restrict__ dst,
                                                      const int* __restrict__ CD, const int* __restrict__ CS,
                                                      const int* __restrict__ BSD, const int* __restrict__ BSS,
                                                      int* __restrict__ binnedD,
                                                      unsigned char* __restrict__ srcb,
                                                      int E, int chunk) {
    __shared__ int curD[NT], curS[NT];
    const int t = threadIdx.x, blk = blockIdx.x;
    for (int i = t; i < NT; i += 256) {
        int idx = i * NB + blk;
        curD[i] = CD[idx] + BSD[idx >> 12];
        curS[i] = CS[idx] + BSS[idx >> 12];
    }
    __syncthreads();
    const int lo = blk * chunk;
    int hi = lo + chunk; if (hi > E) hi = E;
    for (int i = lo + t; i < hi; i += 256) {
        int s = src[i], d = dst[i];
        int p = atomicAdd(&curD[d >> 7], 1);
        binnedD[p] = (s << 7) | (d & 127);
        int ps = atomicAdd(&curS[s >> 7], 1);
        srcb[ps] = (unsigned char)(s & 127);
    }
}

// ---------------- pass 4: per-tile CSR-ify (dst) + deg_out histogram (src) ----------------
__global__ __launch_bounds__(256) void tile_kernel(const int* __restrict__ CD, const int* __restrict__ CS,
                                                   const int* __restrict__ BSD, const int* __restrict__ BSS,
                                                   const int* __restrict__ binnedD,
                                                   const unsigned char* __restrict__ srcb,
                                                   int* __restrict__ csr,
                                                   int* __restrict__ offs, int* __restrict__ cnt,
                                                   int* __restrict__ deg_out, int E) {
    __shared__ int h[128], cur[128];
    __shared__ int w0tot;
    const int bin = blockIdx.x, t = threadIdx.x, lane = t & 63;
    const int i0 = bin * NB;

    // ---- dst phase: histogram 128 nodes, scan, write offs/cnt, place CSR ----
    if (t < 128) h[t] = 0;
    __syncthreads();
    const int base = CD[i0] + BSD[i0 >> 12];
    const int next = (bin + 1 < NT) ? (CD[i0 + NB] + BSD[(i0 + NB) >> 12]) : E;
    const int m = next - base;
    for (int k = t; k < m; k += 256) atomicAdd(&h[binnedD[base + k] & 127], 1);
    __syncthreads();
    int v = (t < 128) ? h[t] : 0;
    int incl = v;
#pragma unroll
    for (int off = 1; off < 64; off <<= 1) {
        int y = __shfl_up(incl, off);
        if (lane >= off) incl += y;
    }
    if (t == 63) w0tot = incl;
    __syncthreads();
    int excl = incl - v + ((t >= 64 && t < 128) ? w0tot : 0);
    if (t < 128) {
        cur[t] = excl;
        int node = bin * 128 + t;
        if (node < N_NODES) { offs[node] = base + excl; cnt[node] = v; }
    }
    __syncthreads();
    for (int k = t; k < m; k += 256) {
        int rec = binnedD[base + k];
        int p = atomicAdd(&cur[rec & 127], 1);
        csr[base + p] = rec >> 7;
    }

    // ---- src phase: histogram the byte stream -> deg_out ----
    __syncthreads();
    if (t < 128) h[t] = 0;
    __syncthreads();
    const int sb = CS[i0] + BSS[i0 >> 12];
    const int sn = (bin + 1 < NT) ? (CS[i0 + NB] + BSS[(i0 + NB) >> 12]) : E;
    const int sm = sn - sb;
    for (int k = t; k < sm; k += 256) atomicAdd(&h[srcb[sb + k]], 1);
    __syncthreads();
    if (t < 128) {
        int node = bin * 128 + t;
        if (node < N_NODES) deg_out[node] = h[t];
    }
}

// ---------------- MFMA GEMM: x = fp16(h) @ fp16(W), row-scaled by rsqrt(deg_out) in epilogue ----------------
#define A_LD 136
__global__ __launch_bounds__(256) void gemm_kernel(const float* __restrict__ hmat,
                                                   const float* __restrict__ W,
                                                   const int* __restrict__ deg_out,
                                                   __half* __restrict__ xh) {
    __shared__ _Float16 sA[64 * A_LD];
    __shared__ _Float16 sB[64 * A_LD];
    const int t = threadIdx.x;
    const int lane = t & 63;
    const int w = t >> 6;
    const int row0 = blockIdx.x * 64;
    const int m0 = (w & 1) * 32;
    const int n0 = (w >> 1) * 32;

    f32x4 acc00 = {0.f, 0.f, 0.f, 0.f}, acc01 = {0.f, 0.f, 0.f, 0.f};
    f32x4 acc10 = {0.f, 0.f, 0.f, 0.f}, acc11 = {0.f, 0.f, 0.f, 0.f};

    for (int khalf = 0; khalf < 2; ++khalf) {
        const int k0 = khalf * 128;
        __syncthreads();
#pragma unroll
        for (int it = 0; it < 8; ++it) {
            int f = t + it * 256;
            int row = f >> 5;
            int c4 = f & 31;
            int grow = row0 + row; if (grow >= N_NODES) grow = N_NODES - 1;
            float4 v = *(const float4*)(hmat + (size_t)grow * IN_DIM + k0 + c4 * 4);
            _Float16 p[4];
            p[0] = (_Float16)v.x; p[1] = (_Float16)v.y;
            p[2] = (_Float16)v.z; p[3] = (_Float16)v.w;
            *(uint2*)&sA[row * A_LD + c4 * 4] = *(uint2*)p;
        }
        {
            int n = t & 63;
            int kk0 = (t >> 6) * 32;
#pragma unroll
            for (int kb = 0; kb < 8; ++kb) {
                _Float16 p[4];
#pragma unroll
                for (int u = 0; u < 4; ++u)
                    p[u] = (_Float16)W[(size_t)(k0 + kk0 + kb * 4 + u) * OUT_DIM + n];
                *(uint2*)&sB[n * A_LD + kk0 + kb * 4] = *(uint2*)p;
            }
        }
        __syncthreads();
#pragma unroll
        for (int kb = 0; kb < 4; ++kb) {
            int koff = kb * 32 + (lane >> 4) * 8;
            half8 a0 = *(const half8*)&sA[(m0 + (lane & 15)) * A_LD + koff];
            half8 a1 = *(const half8*)&sA[(m0 + 16 + (lane & 15)) * A_LD + koff];
            half8 b0 = *(const half8*)&sB[(n0 + (lane & 15)) * A_LD + koff];
            half8 b1 = *(const half8*)&sB[(n0 + 16 + (lane & 15)) * A_LD + koff];
            acc00 = __builtin_amdgcn_mfma_f32_16x16x32_f16(a0, b0, acc00, 0, 0, 0);
            acc01 = __builtin_amdgcn_mfma_f32_16x16x32_f16(a0, b1, acc01, 0, 0, 0);
            acc10 = __builtin_amdgcn_mfma_f32_16x16x32_f16(a1, b0, acc10, 0, 0, 0);
            acc11 = __builtin_amdgcn_mfma_f32_16x16x32_f16(a1, b1, acc11, 0, 0, 0);
        }
    }

    const int col16 = lane & 15;
    const int rq = (lane >> 4) * 4;
#pragma unroll
    for (int mi = 0; mi < 2; ++mi) {
        float nrm[4];
#pragma unroll
        for (int r = 0; r < 4; ++r) {
            int row = row0 + m0 + mi * 16 + rq + r;
            int d = (row < N_NODES) ? deg_out[row] : 1;
            nrm[r] = rsqrtf((float)(d < 1 ? 1 : d));
        }
#pragma unroll
        for (int ni = 0; ni < 2; ++ni) {
            const f32x4 a = (mi == 0) ? (ni == 0 ? acc00 : acc01)
                                      : (ni == 0 ? acc10 : acc11);
            int col = n0 + ni * 16 + col16;
#pragma unroll
            for (int r = 0; r < 4; ++r) {
                int row = row0 + m0 + mi * 16 + rq + r;
                if (row < N_NODES)
                    xh[(size_t)row * OUT_DIM + col] = __float2half(a[r] * nrm[r]);
            }
        }
    }
}

// ---------------- aggregate: one wave per node; FULL 64-edge stage in flight ----------------
// g = lane>>3 (edge group), c = lane&7 (16B col-block). 8 uint4 loads per lane in flight
// (128 B/lane outstanding, 2x the R7 depth) — typical deg~16 nodes now issue their whole
// neighbor list in one burst instead of two serialized half-bursts.
__global__ __launch_bounds__(256) void aggregate_kernel(const int* __restrict__ offs,
                                                        const int* __restrict__ cnt,
                                                        const int* __restrict__ csr,
                                                        const __half* __restrict__ xh,
                                                        const float* __restrict__ b,
                                                        float* __restrict__ out) {
    const int t = threadIdx.x;
    const int lane = t & 63;
    const int wid = t >> 6;
    const int node = blockIdx.x * 4 + wid;          // 25000*4 == N_NODES exactly
    const int g = lane >> 3;
    const int c = lane & 7;

    const int start = offs[node];
    const int n = cnt[node];

    float acc[8] = {0.f, 0.f, 0.f, 0.f, 0.f, 0.f, 0.f, 0.f};
    for (int base = 0; base < n; base += 64) {
        int k = base + lane;
        int sidx = (k < n) ? csr[start + k] : 0;
        int m = n - base; if (m > 64) m = 64;
        uint4 raw[8]; float wq[8];
#pragma unroll
        for (int q = 0; q < 8; ++q) {
            int e = 8 * q + g;                       // covers 0..63
            int s = __shfl(sidx, e);
            bool val = e < m;
            s = val ? s : 0;
            wq[q] = val ? 1.f : 0.f;
            raw[q] = *(const uint4*)(xh + (size_t)s * OUT_DIM + 8 * c);
        }
#pragma unroll
        for (int q = 0; q < 8; ++q) {
            const __half2* hp = (const __half2*)&raw[q];
#pragma unroll
            for (int p = 0; p < 4; ++p) {
                float2 f = __half22float2(hp[p]);
                acc[2 * p]     = fmaf(wq[q], f.x, acc[2 * p]);
                acc[2 * p + 1] = fmaf(wq[q], f.y, acc[2 * p + 1]);
            }
        }
    }

#pragma unroll
    for (int off = 8; off < 64; off <<= 1) {
#pragma unroll
        for (int p = 0; p < 8; ++p)
            acc[p] += __shfl_xor(acc[p], off);
    }

    if (g == 0) {   // lanes 0..7 hold full sums for cols c*8..c*8+7
        float nrm = rsqrtf((float)(n < 1 ? 1 : n));
        float4 bv0 = *(const float4*)&b[c * 8];
        float4 bv1 = *(const float4*)&b[c * 8 + 4];
        float4 r0, r1;
        r0.x = fmaxf(fmaf(acc[0], nrm, bv0.x), 0.f);
        r0.y = fmaxf(fmaf(acc[1], nrm, bv0.y), 0.f);
        r0.z = fmaxf(fmaf(acc[2], nrm, bv0.z), 0.f);
        r0.w = fmaxf(fmaf(acc[3], nrm, bv0.w), 0.f);
        r1.x = fmaxf(fmaf(acc[4], nrm, bv1.x), 0.f);
        r1.y = fmaxf(fmaf(acc[5], nrm, bv1.y), 0.f);
        r1.z = fmaxf(fmaf(acc[6], nrm, bv1.z), 0.f);
        r1.w = fmaxf(fmaf(acc[7], nrm, bv1.w), 0.f);
        float4* orow = (float4*)(out + (size_t)node * OUT_DIM + c * 8);
        orow[0] = r0;
        orow[1] = r1;
    }
}

extern "C" void kernel_launch(void* const* d_in, const int* in_sizes, int n_in,
                              void* d_out, int out_size, void* d_ws, size_t ws_size,
                              hipStream_t stream) {
    const float* h   = (const float*)d_in[0];
    const int*   src = (const int*)d_in[1];
    const int*   dst = (const int*)d_in[2];
    const float* W   = (const float*)d_in[3];
    const float* b   = (const float*)d_in[4];
    float* out = (float*)d_out;
    const int E = in_sizes[1];
    const int chunk = (E + NB - 1) / NB;

    // workspace layout (16B aligned), total ~30 MB; everything is written before read
    char* ws = (char*)d_ws;
    int*           CD      = (int*)(ws);                    // NT*NB ints (800,768 B)
    int*           CS      = (int*)(ws + 800768);           // NT*NB ints
    int*           BSD     = (int*)(ws + 1601536);          // SB ints (padded 256 B)
    int*           BSS     = (int*)(ws + 1601792);          // SB ints
    int*           binnedD = (int*)(ws + 1602048);          // E ints  (6.4 MB)
    unsigned char* srcb    = (unsigned char*)(ws + 8002048);// E bytes (1.6 MB)
    int*           csr     = (int*)(ws + 9602048);          // E ints  (6.4 MB)
    int*           offs    = (int*)(ws + 16002048);         // N ints
    int*           cntA    = (int*)(ws + 16402048);         // N ints
    int*           deg_out = (int*)(ws + 16802048);         // N ints
    __half*        xh      = (__half*)(ws + 17202048);      // N*64 halfs (12.8 MB)

    count_kernel<<<NB, 256, 0, stream>>>(src, dst, CD, CS, E, chunk);
    scan_blocks_kernel<<<2 * SB, 256, 0, stream>>>(CD, CS, BSD, BSS);
    scan_sums_kernel<<<1, 128, 0, stream>>>(BSD, BSS);
    scatter_kernel<<<NB, 256, 0, stream>>>(src, dst, CD, CS, BSD, BSS, binnedD, srcb, E, chunk);
    tile_kernel<<<NT, 256, 0, stream>>>(CD, CS, BSD, BSS, binnedD, srcb, csr, offs, cntA, deg_out, E);
    gemm_kernel<<<(N_NODES + 63) / 64, 256, 0, stream>>>(h, W, deg_out, xh);
    aggregate_kernel<<<N_NODES / 4, 256, 0, stream>>>(offs, cntA, csr, xh, b, out);
}